// Round 3
// baseline (120.734 us; speedup 1.0000x reference)
//
#include <hip/hip_runtime.h>

// IndexedLinear: out[z, s*V:(s+1)*V] = coeff[s] * x[z, s*U:(s+1)*U] @ W[seg(z), s]
// S=8, U=V=32, C=32 segments, Z=65536. HBM-bound: ~129 MiB -> ~20.5us @ 6.3TB/s.
//
// R8: ZERO-LDS direct streaming. Evidence: R5 (5 blk/CU, sync drains) and R6
// (2 blk/CU, counted-vmcnt dbuf pipeline) benched IDENTICAL (117.9 vs 118.2)
// => limiter is the shared global_load_lds + barrier + LDS round-trip, not
// occupancy/pipelining. Also: kernel absent from rocprof top-5 (all 42us
// fills) => kernel < 42us; bench includes ~85us of harness fills.
//
// Key insight: the MFMA A-fragment for 32x32x16 needs lane (m,h) to hold
// x[row m][k = 8h..8h+8) -- a CONTIGUOUS 32B row slice. No transpose needed:
// load straight from global (2x dwordx4 per k-half). The 4 loads of one
// s-tile jointly consume each 128B line exactly once (L1/L2 temporal reuse
// within the wave) -> HBM traffic unchanged (64 MiB X), no DMA engine, no
// barriers, no LDS. Pure load->MFMA->NT-store streaming, ~20 waves/CU.
//  - B fragments (W slice, coeff folded) via v_cvt_pk_bf16_f32 (RNE,
//    bit-identical to prior f2bf; 12 VALU per 8 elems vs 32).
//  - Verified C/D store map carried from R5/R6 (2 full 128B lines per store).
//  - fp32 boundary fallback (exact) now reads X directly; no barriers on
//    either path (waves fully independent).

constexpr int S = 8, U = 32, V = 32, C = 32, Z = 65536;
constexpr int SU = S * U;   // 256 floats per X row
constexpr int SV = S * V;   // 256 floats per out row
constexpr int NT = 256;     // 4 waves
constexpr int BZ = 32;      // z rows per block; wave w handles s in {2w, 2w+1}

typedef float    f4     __attribute__((ext_vector_type(4)));
typedef float    f32x16 __attribute__((ext_vector_type(16)));
typedef short    bf16x8 __attribute__((ext_vector_type(8)));
typedef unsigned u32x4  __attribute__((ext_vector_type(4)));

// packed RNE f32x2 -> bf16x2 (low = lo, high = hi); bit-identical to manual
// round-to-nearest-even f2bf used in prior verified rounds.
__device__ __forceinline__ unsigned cvtpk(float lo, float hi) {
  unsigned r;
  asm("v_cvt_pk_bf16_f32 %0, %1, %2" : "=v"(r) : "v"(lo), "v"(hi));
  return r;
}

__global__ __launch_bounds__(NT) void IndexedLinear_kernel(
    const float* __restrict__ W_all,   // (C, S*U*V)
    const float* __restrict__ X,       // (Z, S*U)
    const int*   __restrict__ counts,  // (C,)
    const float* __restrict__ coeff,   // (S,)
    float*       __restrict__ out)     // (Z, S*V)
{
  const int tid  = threadIdx.x;
  const int lane = tid & 63;
  const int w    = tid >> 6;
  const int z0   = blockIdx.x * BZ;

  const int m  = lane & 31;   // A row / B col / C col
  const int h  = lane >> 5;   // k-half
  const int s0 = 2 * w;

  // ---- segment exclusive-prefix scan (per wave, no cross-wave dependency) --
  int cnt = (lane < C) ? counts[lane] : 0;
  int inc = cnt;
  #pragma unroll
  for (int d = 1; d < 32; d <<= 1) {
    int o = __shfl_up(inc, d, 64);
    if (lane >= d) inc += o;
  }
  const int exc = inc - cnt;
  const unsigned long long ma = __ballot(lane < C && exc <= z0);
  const unsigned long long mb = __ballot(lane < C && exc <= z0 + BZ - 1);
  const int segA = __popcll(ma) - 1;
  const int segB = __popcll(mb) - 1;
  const bool uni = (segA == segB);

  if (uni) {
    // ---- A: direct global loads, lane (m,h) reads its contiguous 32B row
    //      slices for both s-tiles (8x global_load_dwordx4, max MLP) ----
    const f4* Xr = (const f4*)X + (size_t)(z0 + m) * (SU / 4) + 2 * h;
    f4 xs[8];
    #pragma unroll
    for (int tt = 0; tt < 2; ++tt) {
      const int c0 = (s0 + tt) * 8;
      xs[4 * tt + 0] = Xr[c0 + 0];   // a1 lo:  k = 8h   .. 8h+4
      xs[4 * tt + 1] = Xr[c0 + 1];   // a1 hi:  k = 8h+4 .. 8h+8
      xs[4 * tt + 2] = Xr[c0 + 4];   // a2 lo:  k = 16+8h ..
      xs[4 * tt + 3] = Xr[c0 + 5];   // a2 hi
    }

    // ---- B fragments (L2-hot W, coeff folded), packed converts ----
    const float* wseg = W_all + (size_t)segA * (S * U * V);
    u32x4 b1[2], b2[2];
    #pragma unroll
    for (int tt = 0; tt < 2; ++tt) {
      const int s = s0 + tt;
      const float cs = coeff[s];
      const float* wb = wseg + s * (U * V) + m;
      #pragma unroll
      for (int j = 0; j < 4; ++j) {
        b1[tt][j] = cvtpk(wb[(8 * h + 2 * j) * V] * cs,
                          wb[(8 * h + 2 * j + 1) * V] * cs);
        b2[tt][j] = cvtpk(wb[(16 + 8 * h + 2 * j) * V] * cs,
                          wb[(16 + 8 * h + 2 * j + 1) * V] * cs);
      }
    }

    #pragma unroll
    for (int tt = 0; tt < 2; ++tt) {
      const int s = s0 + tt;
      const f4 xa = xs[4 * tt + 0], xb = xs[4 * tt + 1];
      const f4 xc = xs[4 * tt + 2], xd = xs[4 * tt + 3];
      u32x4 pa, pb;
      pa[0] = cvtpk(xa[0], xa[1]); pa[1] = cvtpk(xa[2], xa[3]);
      pa[2] = cvtpk(xb[0], xb[1]); pa[3] = cvtpk(xb[2], xb[3]);
      pb[0] = cvtpk(xc[0], xc[1]); pb[1] = cvtpk(xc[2], xc[3]);
      pb[2] = cvtpk(xd[0], xd[1]); pb[3] = cvtpk(xd[2], xd[3]);
      const bf16x8 a1 = __builtin_bit_cast(bf16x8, pa);
      const bf16x8 a2 = __builtin_bit_cast(bf16x8, pb);
      f32x16 acc = {};
      acc = __builtin_amdgcn_mfma_f32_32x32x16_bf16(
          a1, __builtin_bit_cast(bf16x8, b1[tt]), acc, 0, 0, 0);
      acc = __builtin_amdgcn_mfma_f32_32x32x16_bf16(
          a2, __builtin_bit_cast(bf16x8, b2[tt]), acc, 0, 0, 0);

      // verified C/D map: reg r -> row (r&3)+8*(r>>2)+4h, col m.
      // each store covers 2 full 128B lines (h=0: row R; h=1: row R+4).
      float* ob = out + (size_t)z0 * SV + s * V + m;
      #pragma unroll
      for (int r = 0; r < 16; ++r) {
        const int row = (r & 3) + 8 * (r >> 2) + 4 * h;
        __builtin_nontemporal_store(acc[r], ob + (size_t)row * SV);
      }
    }
  } else {
    // ---- fallback: block crosses a segment boundary (fp32 exact) ----
    const int zz = z0 + m;
    int sg = 0;
    #pragma unroll 1
    for (int i = 1; i < C; ++i) {
      const int pi = __shfl(exc, i, 64);
      if (pi <= zz) sg = i;
    }
    #pragma unroll 1
    for (int tt = 0; tt < 2; ++tt) {
      const int s = s0 + tt;
      const float cs = coeff[s];
      const float* wr = W_all + (size_t)sg * (S * U * V) + s * (U * V) + 16 * h;
      float accv[16] = {};
      #pragma unroll 1
      for (int cq = 0; cq < 8; ++cq) {
        const f4 xv = ((const f4*)X)[(size_t)zz * (SU / 4) + s * 8 + cq];
        #pragma unroll
        for (int ii = 0; ii < 4; ++ii) {
          const int u = cq * 4 + ii;
          const float xu = xv[ii];
          #pragma unroll
          for (int j = 0; j < 16; ++j) accv[j] += xu * wr[u * V + j];
        }
      }
      float* ob = out + (size_t)zz * SV + s * V + 16 * h;
      #pragma unroll
      for (int j = 0; j < 16; ++j) ob[j] = accv[j] * cs;
    }
  }
}

extern "C" void kernel_launch(void* const* d_in, const int* in_sizes, int n_in,
                              void* d_out, int out_size, void* d_ws, size_t ws_size,
                              hipStream_t stream) {
  const float* input1       = (const float*)d_in[0];  // (C, S*U*V)
  const float* input2       = (const float*)d_in[1];  // (Z, S*U)
  const int*   counts       = (const int*)d_in[2];    // (C,)
  const float* coefficients = (const float*)d_in[3];  // (S,)
  float*       out          = (float*)d_out;          // (Z, S*V)

  const int grid = Z / BZ;  // 2048 blocks, 4 independent waves each, no LDS
  IndexedLinear_kernel<<<grid, NT, 0, stream>>>(input1, input2, counts,
                                                coefficients, out);
}